// Round 17
// baseline (173.916 us; speedup 1.0000x reference)
//
#include <hip/hip_runtime.h>

// GraphSAGE 2-layer forward.
// Round 17: abandon counted-vmcnt-with-stores (fragile class: 2 of 3 variants
// raced). Same benefit, robust construction: DEFER all C stores to after the
// K/N loop (acc for all NT tiles lives in registers, +32 VGPR). During the
// loop the only VMEM in flight is the 4 staging loads, so plain
// __syncthreads() (compiler-managed drain) waits exactly on them -- no asm
// waits, no exec-mask sensitivity. Stores pipeline freely in the epilogue.
// Everything else = r14 (last known-good, 173.7us).

#define N_NODES 50000
#define N_EDGES 800000
#define RNB 196
#define REPB 4096
#define BCAP 8192

typedef unsigned short ushort_t;
typedef __attribute__((ext_vector_type(8))) short short8v;   // 8 bf16
typedef __attribute__((ext_vector_type(4))) float f32x4;
typedef __attribute__((ext_vector_type(2))) float f32x2;

__device__ __forceinline__ float b2f(ushort_t u) {
    union { unsigned int i; float f; } v; v.i = (unsigned int)u << 16; return v.f;
}
__device__ __forceinline__ ushort_t f2b(float f) {
    union { float f; unsigned int i; } v; v.f = f;
    unsigned int r = 0x7fffu + ((v.i >> 16) & 1u);   // RNE
    return (ushort_t)((v.i + r) >> 16);
}

__device__ __forceinline__ void gload_lds16(const void* gsrc, void* ldsdst) {
    auto* l3 = reinterpret_cast<__attribute__((address_space(3))) unsigned int*>(
        reinterpret_cast<uintptr_t>(ldsdst));
    __builtin_amdgcn_global_load_lds(
        reinterpret_cast<const unsigned int*>(gsrc), l3, 16, 0, 0);
}

// ================= GEMM core: A-stationary, 32-col B tiles ================
// Block: 256 thr = 4 waves x 16 rows = 64 rows; g = col group (NT x 32
// cols); A-slice (16 rows x 256 k) resident in 8 short8v. B tile 16 KB:
// 4 k-chunks x [32 cols][128 B], XOR (col&7)<<4 (0-conflict, r11-proven).
// ALL stores deferred to epilogue -> loop VMEM = staging loads only ->
// __syncthreads() drains exactly those (safe, compiler-managed).
template<int NT, int MODE>
__device__ __forceinline__ void gemm32_core(
    int g, int ry, int t, const ushort_t* __restrict__ A,
    const ushort_t* __restrict__ Bt, const float* __restrict__ bias,
    unsigned char* __restrict__ out8, ushort_t* __restrict__ outb,
    float* __restrict__ outf, int M, char* Bs)
{
    const int lane = t & 63;
    const int wv   = t >> 6;
    const int row0 = ry * 64 + wv * 16;
    const int cbase = g * NT * 32;
    const int arow = min(row0 + (lane & 15), M - 1);
    const int kq   = (lane >> 4) << 3;

    auto stage = [&](int ct) {
        #pragma unroll
        for (int c = 0; c < 4; ++c) {
            int o    = t * 16;                       // 0..4095 in chunk
            int colI = o >> 7;
            int kb   = (o & 127) ^ ((colI & 7) << 4);
            gload_lds16(Bt + (size_t)(cbase + ct * 32 + colI) * 256
                           + c * 64 + (kb >> 1),
                        Bs + c * 4096 + wv * 1024);
        }
    };

    short8v af[8];
    #pragma unroll
    for (int ks = 0; ks < 8; ++ks)
        af[ks] = *(const short8v*)(A + (size_t)arow * 256 + ks * 32 + kq);

    stage(0);
    __syncthreads();                       // drains A + B(0) loads

    f32x4 acc[NT][2] = {};

    #pragma unroll
    for (int ct = 0; ct < NT; ++ct) {
        __builtin_amdgcn_s_setprio(1);
        #pragma unroll
        for (int ks = 0; ks < 8; ++ks) {
            #pragma unroll
            for (int nj = 0; nj < 2; ++nj) {
                int colI = (nj << 4) + (lane & 15);
                int b = (((ks & 1) << 6) + ((lane >> 4) << 4))
                        ^ ((colI & 7) << 4);
                short8v bg = *(const short8v*)(Bs + (ks >> 1) * 4096
                                               + colI * 128 + b);
                acc[ct][nj] = __builtin_amdgcn_mfma_f32_16x16x32_bf16(
                    af[ks], bg, acc[ct][nj], 0, 0, 0);
            }
        }
        __builtin_amdgcn_s_setprio(0);

        if (ct + 1 < NT) {
            __syncthreads();               // all waves done reading Bs
            stage(ct + 1);                 // 4 loads (only VMEM in flight)
            __syncthreads();               // drain -> Bs(ct+1) valid
        }
    }

    // epilogue: all stores at once (pipeline freely; nothing waits on them)
    #pragma unroll
    for (int ct = 0; ct < NT; ++ct) {
        #pragma unroll
        for (int nj = 0; nj < 2; ++nj) {
            int c = cbase + ct * 32 + (nj << 4) + (lane & 15);
            #pragma unroll
            for (int r = 0; r < 4; ++r) {
                int row = row0 + ((lane >> 4) << 2) + r;
                if (row >= M) continue;
                float v = acc[ct][nj][r];
                if (MODE == 0) {
                    if (g < 2) {
                        unsigned p = __builtin_amdgcn_cvt_pk_fp8_f32(v, v, 0, false);
                        out8[(size_t)row * 256 + c] = (unsigned char)(p & 0xFFu);
                    } else {
                        outb[(size_t)row * 256 + (c - 256)] = f2b(v + bias[c - 256]);
                    }
                } else {
                    if (g < 2) {
                        outb[(size_t)row * 128 + c] = f2b(v);
                    } else {
                        outf[(size_t)row * 128 + (c - 128)] = v + bias[c - 128];
                    }
                }
            }
        }
    }
}

// ================= K1: mhist || cast_f32_bf16 || build_bt =================
__global__ __launch_bounds__(256) void fusedA(
    const int* __restrict__ ei, int* __restrict__ ghist,
    const float* __restrict__ x, ushort_t* __restrict__ xb,
    const float* __restrict__ W1l, const float* __restrict__ W1r,
    const float* __restrict__ W2l, const float* __restrict__ W2r,
    ushort_t* __restrict__ Bt1, ushort_t* __restrict__ Bt2, int E)
{
    __shared__ int hh[256];
    int bid = blockIdx.x, t = threadIdx.x;

    if (bid < RNB) {                         // ---- mhist ----
        hh[t] = 0;
        __syncthreads();
        int base = bid * REPB;
        int lim  = min(base + REPB, E);
        for (int i = base + t; i < lim; i += 256)
            atomicAdd(&hh[ei[E + i] >> 8], 1);
        __syncthreads();
        if (t < RNB) ghist[t * RNB + bid] = hh[t];
    } else if (bid < RNB + 800) {            // ---- cast (800 blocks) ----
        int n4 = N_NODES * 256 / 4;
        int i = (bid - RNB) * 256 + t;
        for (; i < n4; i += 800 * 256) {
            float4 v = ((const float4*)x)[i];
            ushort4 o;
            o.x = f2b(v.x); o.y = f2b(v.y); o.z = f2b(v.z); o.w = f2b(v.w);
            ((ushort4*)xb)[i] = o;
        }
    } else {                                 // ---- build_bt (768 blocks) ----
        int i = (bid - RNB - 800) * 256 + t;
        if (i < 512 * 256) {
            int n = i >> 8, k = i & 255;
            float v = (n < 256) ? W1l[k * 256 + n] : W1r[k * 256 + (n - 256)];
            Bt1[i] = f2b(v);
        }
        int j = i - 512 * 256;
        if (j >= 0 && j < 256 * 256) {
            int n = j >> 8, k = j & 255;
            float v = (n < 128) ? W2l[k * 128 + n] : W2r[k * 128 + (n - 128)];
            Bt2[j] = f2b(v);
        }
    }
}

// ================= scans =================
#define SCAN_B 256
__global__ __launch_bounds__(256) void scan1(
    const int* __restrict__ in, int* __restrict__ excl,
    int* __restrict__ bsum, int N)
{
    __shared__ int s[SCAN_B];
    int t = threadIdx.x;
    int i = blockIdx.x * SCAN_B + t;
    int v = (i < N) ? in[i] : 0;
    s[t] = v;
    __syncthreads();
    for (int off = 1; off < SCAN_B; off <<= 1) {
        int add = (t >= off) ? s[t - off] : 0;
        __syncthreads();
        s[t] += add;
        __syncthreads();
    }
    if (i < N) excl[i] = s[t] - v;
    if (t == SCAN_B - 1) bsum[blockIdx.x] = s[t];
}

__global__ __launch_bounds__(256) void scan2(int* __restrict__ bsum, int nb)
{
    __shared__ int s[SCAN_B];
    int t = threadIdx.x;
    int v = (t < nb) ? bsum[t] : 0;
    s[t] = v;
    __syncthreads();
    for (int off = 1; off < 256; off <<= 1) {
        int add = (t >= off) ? s[t - off] : 0;
        __syncthreads();
        s[t] += add;
        __syncthreads();
    }
    if (t < nb) bsum[t] = s[t] - v;
}

__global__ __launch_bounds__(256) void scan3g(
    int* __restrict__ excl, const int* __restrict__ bsum, int N)
{
    int i = blockIdx.x * SCAN_B + threadIdx.x;
    if (i < N) excl[i] += bsum[blockIdx.x];
}

// ================= K3: mscatter || GEMM1 (MODE 0) =================
__global__ __launch_bounds__(256, 4) void fusedB(
    const int* __restrict__ ei, const int* __restrict__ gscan,
    unsigned* __restrict__ packed,
    const ushort_t* __restrict__ A, const ushort_t* __restrict__ Bt,
    const float* __restrict__ bias, unsigned char* __restrict__ out8,
    ushort_t* __restrict__ outb, int E, int M)
{
    __shared__ char BsMem[16384];
    __shared__ int  curMem[256];
    int bid = blockIdx.x, t = threadIdx.x;

    if (bid < RNB) {                         // ---- mscatter ----
        if (t < RNB) curMem[t] = gscan[t * RNB + bid];
        __syncthreads();
        int base = bid * REPB;
        int lim  = min(base + REPB, E);
        for (int i = base + t; i < lim; i += 256) {
            int d = ei[E + i], s = ei[i];
            int pos = atomicAdd(&curMem[d >> 8], 1);
            packed[pos] = ((unsigned)d << 16) | (unsigned)s;
        }
    } else {                                 // ---- GEMM1 ----
        int q = bid - RNB;
        gemm32_core<4, 0>(q & 3, q >> 2, t, A, Bt, bias,
                          out8, outb, (float*)nullptr, M, BsMem);
    }
}

// ================= standalone GEMM2 (MODE 1) =================
__global__ __launch_bounds__(256, 4) void gemm2k(
    const ushort_t* __restrict__ A, const ushort_t* __restrict__ Bt,
    const float* __restrict__ bias, ushort_t* __restrict__ outb,
    float* __restrict__ outf, int M)
{
    __shared__ char BsMem[16384];
    gemm32_core<2, 1>(blockIdx.x, blockIdx.y, threadIdx.x, A, Bt, bias,
                      (unsigned char*)nullptr, outb, outf, M, BsMem);
}

// ================= bucket_sort =================
__global__ __launch_bounds__(256) void bucket_sort(
    const unsigned* __restrict__ packed, const int* __restrict__ gscan,
    int* __restrict__ col, int* __restrict__ rp, int E)
{
    __shared__ unsigned k1[BCAP];
    __shared__ unsigned k2[BCAP];
    __shared__ int h[256], ss[256], ex[256], cur[256];

    int b = blockIdx.x, t = threadIdx.x;
    int start = gscan[b * RNB];
    int end   = (b + 1 < RNB) ? gscan[(b + 1) * RNB] : E;
    int sz    = min(end - start, BCAP);

    for (int i = t; i < sz; i += 256) k1[i] = packed[start + i];
    h[t] = 0;
    __syncthreads();
    for (int i = t; i < sz; i += 256)
        atomicAdd(&h[(k1[i] >> 16) & 255], 1);
    __syncthreads();
    ss[t] = h[t];
    __syncthreads();
    for (int off = 1; off < 256; off <<= 1) {
        int add = (t >= off) ? ss[t - off] : 0;
        __syncthreads();
        ss[t] += add;
        __syncthreads();
    }
    ex[t] = ss[t] - h[t];
    cur[t] = ex[t];
    __syncthreads();
    for (int i = t; i < sz; i += 256) {
        unsigned key = k1[i];
        int pos = atomicAdd(&cur[(key >> 16) & 255], 1);
        k2[pos] = key;
    }
    __syncthreads();
    for (int i = t; i < sz; i += 256)
        col[start + i] = (int)(k2[i] & 0xFFFFu);
    int dst = (b << 8) + t;
    if (dst <= N_NODES) rp[dst] = start + ex[t];
}

// ================= gathers =================
__global__ __launch_bounds__(256) void fused_gather1(
    const unsigned char* __restrict__ y8, const ushort_t* __restrict__ y2b,
    const int* __restrict__ rp, const int* __restrict__ col,
    ushort_t* __restrict__ h, int N)
{
    int gid  = blockIdx.x * blockDim.x + threadIdx.x;
    int node = gid >> 6;
    int lane = gid & 63;
    if (node >= N) return;
    int rs = rp[node], re = rp[node + 1];

    float acc[4] = {0.f, 0.f, 0.f, 0.f};
    for (int base = rs; base < re; base += 64) {
        int m = re - base; if (m > 64) m = 64;
        int c = (lane < m) ? col[base + lane] : 0;
        int j = 0;
        for (; j + 8 <= m; j += 8) {
            unsigned tv[8];
            #pragma unroll
            for (int q = 0; q < 8; ++q) {
                int sq = __shfl(c, j + q);
                tv[q] = *(const unsigned*)(y8 + (size_t)sq * 256 + lane * 4);
            }
            #pragma unroll
            for (int q = 0; q < 8; ++q) {
                f32x2 lo = __builtin_amdgcn_cvt_pk_f32_fp8(tv[q], false);
                f32x2 hi = __builtin_amdgcn_cvt_pk_f32_fp8(tv[q], true);
                acc[0] += lo[0]; acc[1] += lo[1];
                acc[2] += hi[0]; acc[3] += hi[1];
            }
        }
        for (; j < m; ++j) {
            int sq = __shfl(c, j);
            unsigned tq = *(const unsigned*)(y8 + (size_t)sq * 256 + lane * 4);
            f32x2 lo = __builtin_amdgcn_cvt_pk_f32_fp8(tq, false);
            f32x2 hi = __builtin_amdgcn_cvt_pk_f32_fp8(tq, true);
            acc[0] += lo[0]; acc[1] += lo[1];
            acc[2] += hi[0]; acc[3] += hi[1];
        }
    }

    float s = 1.0f / (float)max(re - rs, 1);
    ushort4 t2 = *(const ushort4*)(y2b + (size_t)node * 256 + lane * 4);
    ushort4 o;
    o.x = f2b(fmaxf(acc[0] * s + b2f(t2.x), 0.f));
    o.y = f2b(fmaxf(acc[1] * s + b2f(t2.y), 0.f));
    o.z = f2b(fmaxf(acc[2] * s + b2f(t2.z), 0.f));
    o.w = f2b(fmaxf(acc[3] * s + b2f(t2.w), 0.f));
    *(ushort4*)(h + (size_t)node * 256 + lane * 4) = o;
}

__global__ __launch_bounds__(256) void fused_gather2(
    const ushort_t* __restrict__ zb, const int* __restrict__ rp,
    const int* __restrict__ col, float* __restrict__ out, int N)
{
    int gid  = blockIdx.x * blockDim.x + threadIdx.x;
    int node = gid >> 6;
    int lane = gid & 63;
    if (node >= N) return;
    int rs = rp[node], re = rp[node + 1];

    float acc[2] = {0.f, 0.f};
    for (int base = rs; base < re; base += 64) {
        int m = re - base; if (m > 64) m = 64;
        int c = (lane < m) ? col[base + lane] : 0;
        int j = 0;
        for (; j + 8 <= m; j += 8) {
            ushort2 tv[8];
            #pragma unroll
            for (int q = 0; q < 8; ++q) {
                int sq = __shfl(c, j + q);
                tv[q] = *(const ushort2*)(zb + (size_t)sq * 128 + lane * 2);
            }
            #pragma unroll
            for (int q = 0; q < 8; ++q) {
                acc[0] += b2f(tv[q].x); acc[1] += b2f(tv[q].y);
            }
        }
        for (; j < m; ++j) {
            int src = __shfl(c, j);
            ushort2 tq = *(const ushort2*)(zb + (size_t)src * 128 + lane * 2);
            acc[0] += b2f(tq.x); acc[1] += b2f(tq.y);
        }
    }

    float s = 1.0f / (float)max(re - rs, 1);
    float2 p = *(float2*)(out + (size_t)node * 128 + lane * 2);
    p.x += acc[0] * s; p.y += acc[1] * s;
    *(float2*)(out + (size_t)node * 128 + lane * 2) = p;
}

extern "C" void kernel_launch(void* const* d_in, const int* in_sizes, int n_in,
                              void* d_out, int out_size, void* d_ws, size_t ws_size,
                              hipStream_t stream)
{
    const float* x   = (const float*)d_in[0];
    const int*   ei  = (const int*)d_in[1];
    const float* W1l = (const float*)d_in[2];
    const float* b1  = (const float*)d_in[3];
    const float* W1r = (const float*)d_in[4];
    const float* W2l = (const float*)d_in[5];
    const float* b2  = (const float*)d_in[6];
    const float* W2r = (const float*)d_in[7];
    float* out = (float*)d_out;

    const int N = N_NODES, E = N_EDGES;
    const int HTOT = RNB * RNB;

    // workspace layout (256 B aligned)
    const size_t off_rp     = 0;
    const size_t off_col    = 204800;
    const size_t off_packed = off_col + 3200000;
    const size_t off_ghist  = off_packed + 3200000;
    const size_t off_gscan  = off_ghist + 160000;
    const size_t off_bsumR  = off_gscan + 160000;
    const size_t off_xb     = off_bsumR + 2048;                // bf16 [N][256]; h overlays
    const size_t off_y8     = off_xb  + (size_t)N * 256 * 2;   // fp8  [N][256]; zb overlays
    const size_t off_y2b    = off_y8  + (size_t)N * 256;       // bf16 [N][256]
    const size_t off_bt1    = off_y2b + (size_t)N * 256 * 2;
    const size_t off_bt2    = off_bt1 + 512 * 256 * 2;
    const size_t required   = off_bt2 + 256 * 256 * 2;         // ~71.3 MB
    if (ws_size < required) return;

    char* ws = (char*)d_ws;
    int*           rp     = (int*)(ws + off_rp);
    int*           col    = (int*)(ws + off_col);
    unsigned*      packed = (unsigned*)(ws + off_packed);
    int*           ghist  = (int*)(ws + off_ghist);
    int*           gscan  = (int*)(ws + off_gscan);
    int*           bsumR  = (int*)(ws + off_bsumR);
    ushort_t*      xb     = (ushort_t*)(ws + off_xb);
    ushort_t*      h      = (ushort_t*)(ws + off_xb);  // overlays xb (dead after GEMM1)
    unsigned char* y8     = (unsigned char*)(ws + off_y8);
    ushort_t*      zb     = (ushort_t*)(ws + off_y8);  // overlays y8 (dead after gather1)
    ushort_t*      y2b    = (ushort_t*)(ws + off_y2b);
    ushort_t*      Bt1    = (ushort_t*)(ws + off_bt1);
    ushort_t*      Bt2    = (ushort_t*)(ws + off_bt2);

    const int snb  = (HTOT + SCAN_B - 1) / SCAN_B;  // 151
    const int mt64 = (N + 63) / 64;                 // 782 row slabs

    // ---- K1: mhist || cast || build_bt ----
    hipLaunchKernelGGL(fusedA, dim3(RNB + 800 + 768), dim3(256), 0, stream,
                       ei, ghist, x, xb, W1l, W1r, W2l, W2r, Bt1, Bt2, E);

    // ---- scans ----
    hipLaunchKernelGGL(scan1, dim3(snb), dim3(SCAN_B), 0, stream, ghist, gscan, bsumR, HTOT);
    hipLaunchKernelGGL(scan2, dim3(1), dim3(SCAN_B), 0, stream, bsumR, snb);
    hipLaunchKernelGGL(scan3g, dim3(snb), dim3(SCAN_B), 0, stream, gscan, bsumR, HTOT);

    // ---- K3: mscatter || GEMM1 ([y8|y2b] = xb@[W1l|W1r] (+b1)) ----
    hipLaunchKernelGGL(fusedB, dim3(RNB + 4 * mt64), dim3(256), 0, stream,
                       ei, gscan, packed, xb, Bt1, b1, y8, y2b, E, N);

    // ---- bucket_sort -> CSR done ----
    hipLaunchKernelGGL(bucket_sort, dim3(RNB), dim3(256), 0, stream,
                       packed, gscan, col, rp, E);

    // ---- gather1: h = relu(mean(y8) + y2b) ----
    hipLaunchKernelGGL(fused_gather1, dim3((N + 3) / 4), dim3(256), 0, stream,
                       y8, y2b, rp, col, h, N);

    // ---- GEMM2: [zb|out] = h@[W2l|W2r] (+b2 on out) ----
    hipLaunchKernelGGL(gemm2k, dim3(4, mt64), dim3(256), 0, stream,
                       h, Bt2, b2, zb, out, N);

    // ---- gather2: out += mean(zb) ----
    hipLaunchKernelGGL(fused_gather2, dim3((N + 3) / 4), dim3(256), 0, stream,
                       zb, rp, col, out, N);
}

// Round 18
// 171.300 us; speedup vs baseline: 1.0153x; 1.0153x over previous
//
#include <hip/hip_runtime.h>

// GraphSAGE 2-layer forward.
// Round 18: widen GEMM col coverage per block -- GEMM1: NT=8 (2 col-groups
// instead of 4), GEMM2: NT=4 (2 groups). Halves A re-reads (FETCH 54->~41MB)
// and doubles per-block prologue amortization (8 cts per A-load). VGPR
// ~111 <= 128, still (256,4); spills would be harmless (no counted vmcnt --
// r17's deferred-store core, robust by construction). All else = r17.

#define N_NODES 50000
#define N_EDGES 800000
#define RNB 196
#define REPB 4096
#define BCAP 8192

typedef unsigned short ushort_t;
typedef __attribute__((ext_vector_type(8))) short short8v;   // 8 bf16
typedef __attribute__((ext_vector_type(4))) float f32x4;
typedef __attribute__((ext_vector_type(2))) float f32x2;

__device__ __forceinline__ float b2f(ushort_t u) {
    union { unsigned int i; float f; } v; v.i = (unsigned int)u << 16; return v.f;
}
__device__ __forceinline__ ushort_t f2b(float f) {
    union { float f; unsigned int i; } v; v.f = f;
    unsigned int r = 0x7fffu + ((v.i >> 16) & 1u);   // RNE
    return (ushort_t)((v.i + r) >> 16);
}

__device__ __forceinline__ void gload_lds16(const void* gsrc, void* ldsdst) {
    auto* l3 = reinterpret_cast<__attribute__((address_space(3))) unsigned int*>(
        reinterpret_cast<uintptr_t>(ldsdst));
    __builtin_amdgcn_global_load_lds(
        reinterpret_cast<const unsigned int*>(gsrc), l3, 16, 0, 0);
}

// ================= GEMM core: A-stationary, 32-col B tiles ================
// Block: 256 thr = 4 waves x 16 rows = 64 rows; g = col group (NT x 32
// cols); A-slice (16 rows x 256 k) resident in 8 short8v. B tile 16 KB:
// 4 k-chunks x [32 cols][128 B], XOR (col&7)<<4 (0-conflict, r11-proven).
// ALL stores deferred to epilogue -> loop VMEM = staging loads only ->
// __syncthreads() drains exactly those (safe, compiler-managed).
// MODE 0 (N=512, NT=8): g==0 -> y8 fp8 (cols 0..255); g==1 -> y2b bf16+bias.
// MODE 1 (N=256, NT=4): g==0 -> zb bf16 (cols 0..127); g==1 -> outf f32+bias.
template<int NT, int MODE>
__device__ __forceinline__ void gemm32_core(
    int g, int ry, int t, const ushort_t* __restrict__ A,
    const ushort_t* __restrict__ Bt, const float* __restrict__ bias,
    unsigned char* __restrict__ out8, ushort_t* __restrict__ outb,
    float* __restrict__ outf, int M, char* Bs)
{
    const int lane = t & 63;
    const int wv   = t >> 6;
    const int row0 = ry * 64 + wv * 16;
    const int cbase = g * NT * 32;
    const int arow = min(row0 + (lane & 15), M - 1);
    const int kq   = (lane >> 4) << 3;

    auto stage = [&](int ct) {
        #pragma unroll
        for (int c = 0; c < 4; ++c) {
            int o    = t * 16;                       // 0..4095 in chunk
            int colI = o >> 7;
            int kb   = (o & 127) ^ ((colI & 7) << 4);
            gload_lds16(Bt + (size_t)(cbase + ct * 32 + colI) * 256
                           + c * 64 + (kb >> 1),
                        Bs + c * 4096 + wv * 1024);
        }
    };

    short8v af[8];
    #pragma unroll
    for (int ks = 0; ks < 8; ++ks)
        af[ks] = *(const short8v*)(A + (size_t)arow * 256 + ks * 32 + kq);

    stage(0);
    __syncthreads();                       // drains A + B(0) loads

    f32x4 acc[NT][2] = {};

    #pragma unroll
    for (int ct = 0; ct < NT; ++ct) {
        __builtin_amdgcn_s_setprio(1);
        #pragma unroll
        for (int ks = 0; ks < 8; ++ks) {
            #pragma unroll
            for (int nj = 0; nj < 2; ++nj) {
                int colI = (nj << 4) + (lane & 15);
                int b = (((ks & 1) << 6) + ((lane >> 4) << 4))
                        ^ ((colI & 7) << 4);
                short8v bg = *(const short8v*)(Bs + (ks >> 1) * 4096
                                               + colI * 128 + b);
                acc[ct][nj] = __builtin_amdgcn_mfma_f32_16x16x32_bf16(
                    af[ks], bg, acc[ct][nj], 0, 0, 0);
            }
        }
        __builtin_amdgcn_s_setprio(0);

        if (ct + 1 < NT) {
            __syncthreads();               // all waves done reading Bs
            stage(ct + 1);                 // 4 loads (only VMEM in flight)
            __syncthreads();               // drain -> Bs(ct+1) valid
        }
    }

    // epilogue: all stores at once (pipeline freely; nothing waits on them)
    #pragma unroll
    for (int ct = 0; ct < NT; ++ct) {
        #pragma unroll
        for (int nj = 0; nj < 2; ++nj) {
            int c = cbase + ct * 32 + (nj << 4) + (lane & 15);
            #pragma unroll
            for (int r = 0; r < 4; ++r) {
                int row = row0 + ((lane >> 4) << 2) + r;
                if (row >= M) continue;
                float v = acc[ct][nj][r];
                if (MODE == 0) {
                    if (g == 0) {
                        unsigned p = __builtin_amdgcn_cvt_pk_fp8_f32(v, v, 0, false);
                        out8[(size_t)row * 256 + c] = (unsigned char)(p & 0xFFu);
                    } else {
                        outb[(size_t)row * 256 + (c - 256)] = f2b(v + bias[c - 256]);
                    }
                } else {
                    if (g == 0) {
                        outb[(size_t)row * 128 + c] = f2b(v);
                    } else {
                        outf[(size_t)row * 128 + (c - 128)] = v + bias[c - 128];
                    }
                }
            }
        }
    }
}

// ================= K1: mhist || cast_f32_bf16 || build_bt =================
__global__ __launch_bounds__(256) void fusedA(
    const int* __restrict__ ei, int* __restrict__ ghist,
    const float* __restrict__ x, ushort_t* __restrict__ xb,
    const float* __restrict__ W1l, const float* __restrict__ W1r,
    const float* __restrict__ W2l, const float* __restrict__ W2r,
    ushort_t* __restrict__ Bt1, ushort_t* __restrict__ Bt2, int E)
{
    __shared__ int hh[256];
    int bid = blockIdx.x, t = threadIdx.x;

    if (bid < RNB) {                         // ---- mhist ----
        hh[t] = 0;
        __syncthreads();
        int base = bid * REPB;
        int lim  = min(base + REPB, E);
        for (int i = base + t; i < lim; i += 256)
            atomicAdd(&hh[ei[E + i] >> 8], 1);
        __syncthreads();
        if (t < RNB) ghist[t * RNB + bid] = hh[t];
    } else if (bid < RNB + 800) {            // ---- cast (800 blocks) ----
        int n4 = N_NODES * 256 / 4;
        int i = (bid - RNB) * 256 + t;
        for (; i < n4; i += 800 * 256) {
            float4 v = ((const float4*)x)[i];
            ushort4 o;
            o.x = f2b(v.x); o.y = f2b(v.y); o.z = f2b(v.z); o.w = f2b(v.w);
            ((ushort4*)xb)[i] = o;
        }
    } else {                                 // ---- build_bt (768 blocks) ----
        int i = (bid - RNB - 800) * 256 + t;
        if (i < 512 * 256) {
            int n = i >> 8, k = i & 255;
            float v = (n < 256) ? W1l[k * 256 + n] : W1r[k * 256 + (n - 256)];
            Bt1[i] = f2b(v);
        }
        int j = i - 512 * 256;
        if (j >= 0 && j < 256 * 256) {
            int n = j >> 8, k = j & 255;
            float v = (n < 128) ? W2l[k * 128 + n] : W2r[k * 128 + (n - 128)];
            Bt2[j] = f2b(v);
        }
    }
}

// ================= scans =================
#define SCAN_B 256
__global__ __launch_bounds__(256) void scan1(
    const int* __restrict__ in, int* __restrict__ excl,
    int* __restrict__ bsum, int N)
{
    __shared__ int s[SCAN_B];
    int t = threadIdx.x;
    int i = blockIdx.x * SCAN_B + t;
    int v = (i < N) ? in[i] : 0;
    s[t] = v;
    __syncthreads();
    for (int off = 1; off < SCAN_B; off <<= 1) {
        int add = (t >= off) ? s[t - off] : 0;
        __syncthreads();
        s[t] += add;
        __syncthreads();
    }
    if (i < N) excl[i] = s[t] - v;
    if (t == SCAN_B - 1) bsum[blockIdx.x] = s[t];
}

__global__ __launch_bounds__(256) void scan2(int* __restrict__ bsum, int nb)
{
    __shared__ int s[SCAN_B];
    int t = threadIdx.x;
    int v = (t < nb) ? bsum[t] : 0;
    s[t] = v;
    __syncthreads();
    for (int off = 1; off < 256; off <<= 1) {
        int add = (t >= off) ? s[t - off] : 0;
        __syncthreads();
        s[t] += add;
        __syncthreads();
    }
    if (t < nb) bsum[t] = s[t] - v;
}

__global__ __launch_bounds__(256) void scan3g(
    int* __restrict__ excl, const int* __restrict__ bsum, int N)
{
    int i = blockIdx.x * SCAN_B + threadIdx.x;
    if (i < N) excl[i] += bsum[blockIdx.x];
}

// ================= K3: mscatter || GEMM1 (MODE 0, NT=8) =================
__global__ __launch_bounds__(256, 4) void fusedB(
    const int* __restrict__ ei, const int* __restrict__ gscan,
    unsigned* __restrict__ packed,
    const ushort_t* __restrict__ A, const ushort_t* __restrict__ Bt,
    const float* __restrict__ bias, unsigned char* __restrict__ out8,
    ushort_t* __restrict__ outb, int E, int M)
{
    __shared__ char BsMem[16384];
    __shared__ int  curMem[256];
    int bid = blockIdx.x, t = threadIdx.x;

    if (bid < RNB) {                         // ---- mscatter ----
        if (t < RNB) curMem[t] = gscan[t * RNB + bid];
        __syncthreads();
        int base = bid * REPB;
        int lim  = min(base + REPB, E);
        for (int i = base + t; i < lim; i += 256) {
            int d = ei[E + i], s = ei[i];
            int pos = atomicAdd(&curMem[d >> 8], 1);
            packed[pos] = ((unsigned)d << 16) | (unsigned)s;
        }
    } else {                                 // ---- GEMM1 (2 col-groups) ----
        int q = bid - RNB;
        gemm32_core<8, 0>(q & 1, q >> 1, t, A, Bt, bias,
                          out8, outb, (float*)nullptr, M, BsMem);
    }
}

// ================= standalone GEMM2 (MODE 1, NT=4) =================
__global__ __launch_bounds__(256, 4) void gemm2k(
    const ushort_t* __restrict__ A, const ushort_t* __restrict__ Bt,
    const float* __restrict__ bias, ushort_t* __restrict__ outb,
    float* __restrict__ outf, int M)
{
    __shared__ char BsMem[16384];
    gemm32_core<4, 1>(blockIdx.x, blockIdx.y, threadIdx.x, A, Bt, bias,
                      (unsigned char*)nullptr, outb, outf, M, BsMem);
}

// ================= bucket_sort =================
__global__ __launch_bounds__(256) void bucket_sort(
    const unsigned* __restrict__ packed, const int* __restrict__ gscan,
    int* __restrict__ col, int* __restrict__ rp, int E)
{
    __shared__ unsigned k1[BCAP];
    __shared__ unsigned k2[BCAP];
    __shared__ int h[256], ss[256], ex[256], cur[256];

    int b = blockIdx.x, t = threadIdx.x;
    int start = gscan[b * RNB];
    int end   = (b + 1 < RNB) ? gscan[(b + 1) * RNB] : E;
    int sz    = min(end - start, BCAP);

    for (int i = t; i < sz; i += 256) k1[i] = packed[start + i];
    h[t] = 0;
    __syncthreads();
    for (int i = t; i < sz; i += 256)
        atomicAdd(&h[(k1[i] >> 16) & 255], 1);
    __syncthreads();
    ss[t] = h[t];
    __syncthreads();
    for (int off = 1; off < 256; off <<= 1) {
        int add = (t >= off) ? ss[t - off] : 0;
        __syncthreads();
        ss[t] += add;
        __syncthreads();
    }
    ex[t] = ss[t] - h[t];
    cur[t] = ex[t];
    __syncthreads();
    for (int i = t; i < sz; i += 256) {
        unsigned key = k1[i];
        int pos = atomicAdd(&cur[(key >> 16) & 255], 1);
        k2[pos] = key;
    }
    __syncthreads();
    for (int i = t; i < sz; i += 256)
        col[start + i] = (int)(k2[i] & 0xFFFFu);
    int dst = (b << 8) + t;
    if (dst <= N_NODES) rp[dst] = start + ex[t];
}

// ================= gathers =================
__global__ __launch_bounds__(256) void fused_gather1(
    const unsigned char* __restrict__ y8, const ushort_t* __restrict__ y2b,
    const int* __restrict__ rp, const int* __restrict__ col,
    ushort_t* __restrict__ h, int N)
{
    int gid  = blockIdx.x * blockDim.x + threadIdx.x;
    int node = gid >> 6;
    int lane = gid & 63;
    if (node >= N) return;
    int rs = rp[node], re = rp[node + 1];

    float acc[4] = {0.f, 0.f, 0.f, 0.f};
    for (int base = rs; base < re; base += 64) {
        int m = re - base; if (m > 64) m = 64;
        int c = (lane < m) ? col[base + lane] : 0;
        int j = 0;
        for (; j + 8 <= m; j += 8) {
            unsigned tv[8];
            #pragma unroll
            for (int q = 0; q < 8; ++q) {
                int sq = __shfl(c, j + q);
                tv[q] = *(const unsigned*)(y8 + (size_t)sq * 256 + lane * 4);
            }
            #pragma unroll
            for (int q = 0; q < 8; ++q) {
                f32x2 lo = __builtin_amdgcn_cvt_pk_f32_fp8(tv[q], false);
                f32x2 hi = __builtin_amdgcn_cvt_pk_f32_fp8(tv[q], true);
                acc[0] += lo[0]; acc[1] += lo[1];
                acc[2] += hi[0]; acc[3] += hi[1];
            }
        }
        for (; j < m; ++j) {
            int sq = __shfl(c, j);
            unsigned tq = *(const unsigned*)(y8 + (size_t)sq * 256 + lane * 4);
            f32x2 lo = __builtin_amdgcn_cvt_pk_f32_fp8(tq, false);
            f32x2 hi = __builtin_amdgcn_cvt_pk_f32_fp8(tq, true);
            acc[0] += lo[0]; acc[1] += lo[1];
            acc[2] += hi[0]; acc[3] += hi[1];
        }
    }

    float s = 1.0f / (float)max(re - rs, 1);
    ushort4 t2 = *(const ushort4*)(y2b + (size_t)node * 256 + lane * 4);
    ushort4 o;
    o.x = f2b(fmaxf(acc[0] * s + b2f(t2.x), 0.f));
    o.y = f2b(fmaxf(acc[1] * s + b2f(t2.y), 0.f));
    o.z = f2b(fmaxf(acc[2] * s + b2f(t2.z), 0.f));
    o.w = f2b(fmaxf(acc[3] * s + b2f(t2.w), 0.f));
    *(ushort4*)(h + (size_t)node * 256 + lane * 4) = o;
}

__global__ __launch_bounds__(256) void fused_gather2(
    const ushort_t* __restrict__ zb, const int* __restrict__ rp,
    const int* __restrict__ col, float* __restrict__ out, int N)
{
    int gid  = blockIdx.x * blockDim.x + threadIdx.x;
    int node = gid >> 6;
    int lane = gid & 63;
    if (node >= N) return;
    int rs = rp[node], re = rp[node + 1];

    float acc[2] = {0.f, 0.f};
    for (int base = rs; base < re; base += 64) {
        int m = re - base; if (m > 64) m = 64;
        int c = (lane < m) ? col[base + lane] : 0;
        int j = 0;
        for (; j + 8 <= m; j += 8) {
            ushort2 tv[8];
            #pragma unroll
            for (int q = 0; q < 8; ++q) {
                int sq = __shfl(c, j + q);
                tv[q] = *(const ushort2*)(zb + (size_t)sq * 128 + lane * 2);
            }
            #pragma unroll
            for (int q = 0; q < 8; ++q) {
                acc[0] += b2f(tv[q].x); acc[1] += b2f(tv[q].y);
            }
        }
        for (; j < m; ++j) {
            int src = __shfl(c, j);
            ushort2 tq = *(const ushort2*)(zb + (size_t)src * 128 + lane * 2);
            acc[0] += b2f(tq.x); acc[1] += b2f(tq.y);
        }
    }

    float s = 1.0f / (float)max(re - rs, 1);
    float2 p = *(float2*)(out + (size_t)node * 128 + lane * 2);
    p.x += acc[0] * s; p.y += acc[1] * s;
    *(float2*)(out + (size_t)node * 128 + lane * 2) = p;
}

extern "C" void kernel_launch(void* const* d_in, const int* in_sizes, int n_in,
                              void* d_out, int out_size, void* d_ws, size_t ws_size,
                              hipStream_t stream)
{
    const float* x   = (const float*)d_in[0];
    const int*   ei  = (const int*)d_in[1];
    const float* W1l = (const float*)d_in[2];
    const float* b1  = (const float*)d_in[3];
    const float* W1r = (const float*)d_in[4];
    const float* W2l = (const float*)d_in[5];
    const float* b2  = (const float*)d_in[6];
    const float* W2r = (const float*)d_in[7];
    float* out = (float*)d_out;

    const int N = N_NODES, E = N_EDGES;
    const int HTOT = RNB * RNB;

    // workspace layout (256 B aligned)
    const size_t off_rp     = 0;
    const size_t off_col    = 204800;
    const size_t off_packed = off_col + 3200000;
    const size_t off_ghist  = off_packed + 3200000;
    const size_t off_gscan  = off_ghist + 160000;
    const size_t off_bsumR  = off_gscan + 160000;
    const size_t off_xb     = off_bsumR + 2048;                // bf16 [N][256]; h overlays
    const size_t off_y8     = off_xb  + (size_t)N * 256 * 2;   // fp8  [N][256]; zb overlays
    const size_t off_y2b    = off_y8  + (size_t)N * 256;       // bf16 [N][256]
    const size_t off_bt1    = off_y2b + (size_t)N * 256 * 2;
    const size_t off_bt2    = off_bt1 + 512 * 256 * 2;
    const size_t required   = off_bt2 + 256 * 256 * 2;         // ~71.3 MB
    if (ws_size < required) return;

    char* ws = (char*)d_ws;
    int*           rp     = (int*)(ws + off_rp);
    int*           col    = (int*)(ws + off_col);
    unsigned*      packed = (unsigned*)(ws + off_packed);
    int*           ghist  = (int*)(ws + off_ghist);
    int*           gscan  = (int*)(ws + off_gscan);
    int*           bsumR  = (int*)(ws + off_bsumR);
    ushort_t*      xb     = (ushort_t*)(ws + off_xb);
    ushort_t*      h      = (ushort_t*)(ws + off_xb);  // overlays xb (dead after GEMM1)
    unsigned char* y8     = (unsigned char*)(ws + off_y8);
    ushort_t*      zb     = (ushort_t*)(ws + off_y8);  // overlays y8 (dead after gather1)
    ushort_t*      y2b    = (ushort_t*)(ws + off_y2b);
    ushort_t*      Bt1    = (ushort_t*)(ws + off_bt1);
    ushort_t*      Bt2    = (ushort_t*)(ws + off_bt2);

    const int snb  = (HTOT + SCAN_B - 1) / SCAN_B;  // 151
    const int mt64 = (N + 63) / 64;                 // 782 row slabs

    // ---- K1: mhist || cast || build_bt ----
    hipLaunchKernelGGL(fusedA, dim3(RNB + 800 + 768), dim3(256), 0, stream,
                       ei, ghist, x, xb, W1l, W1r, W2l, W2r, Bt1, Bt2, E);

    // ---- scans ----
    hipLaunchKernelGGL(scan1, dim3(snb), dim3(SCAN_B), 0, stream, ghist, gscan, bsumR, HTOT);
    hipLaunchKernelGGL(scan2, dim3(1), dim3(SCAN_B), 0, stream, bsumR, snb);
    hipLaunchKernelGGL(scan3g, dim3(snb), dim3(SCAN_B), 0, stream, gscan, bsumR, HTOT);

    // ---- K3: mscatter || GEMM1 ([y8|y2b] = xb@[W1l|W1r] (+b1)) ----
    hipLaunchKernelGGL(fusedB, dim3(RNB + 2 * mt64), dim3(256), 0, stream,
                       ei, gscan, packed, xb, Bt1, b1, y8, y2b, E, N);

    // ---- bucket_sort -> CSR done ----
    hipLaunchKernelGGL(bucket_sort, dim3(RNB), dim3(256), 0, stream,
                       packed, gscan, col, rp, E);

    // ---- gather1: h = relu(mean(y8) + y2b) ----
    hipLaunchKernelGGL(fused_gather1, dim3((N + 3) / 4), dim3(256), 0, stream,
                       y8, y2b, rp, col, h, N);

    // ---- GEMM2: [zb|out] = h@[W2l|W2r] (+b2 on out) ----
    hipLaunchKernelGGL(gemm2k, dim3(2, mt64), dim3(256), 0, stream,
                       h, Bt2, b2, zb, out, N);

    // ---- gather2: out += mean(zb) ----
    hipLaunchKernelGGL(fused_gather2, dim3((N + 3) / 4), dim3(256), 0, stream,
                       zb, rp, col, out, N);
}

// Round 19
// 170.134 us; speedup vs baseline: 1.0222x; 1.0068x over previous
//
#include <hip/hip_runtime.h>

// GraphSAGE 2-layer forward.
// Round 19: per-kernel NT optimum from r17/r18 A/B: GEMM1 back to NT=4
// (r17: 50.2us @46% occ; NT=8 regressed to 62.6us @32% -- block count
// halved, grid ragged). GEMM2 keeps NT=4 (r18's ~+14us improvement).
// Everything else = r18 (deferred-store core, robust by construction).

#define N_NODES 50000
#define N_EDGES 800000
#define RNB 196
#define REPB 4096
#define BCAP 8192

typedef unsigned short ushort_t;
typedef __attribute__((ext_vector_type(8))) short short8v;   // 8 bf16
typedef __attribute__((ext_vector_type(4))) float f32x4;
typedef __attribute__((ext_vector_type(2))) float f32x2;

__device__ __forceinline__ float b2f(ushort_t u) {
    union { unsigned int i; float f; } v; v.i = (unsigned int)u << 16; return v.f;
}
__device__ __forceinline__ ushort_t f2b(float f) {
    union { float f; unsigned int i; } v; v.f = f;
    unsigned int r = 0x7fffu + ((v.i >> 16) & 1u);   // RNE
    return (ushort_t)((v.i + r) >> 16);
}

__device__ __forceinline__ void gload_lds16(const void* gsrc, void* ldsdst) {
    auto* l3 = reinterpret_cast<__attribute__((address_space(3))) unsigned int*>(
        reinterpret_cast<uintptr_t>(ldsdst));
    __builtin_amdgcn_global_load_lds(
        reinterpret_cast<const unsigned int*>(gsrc), l3, 16, 0, 0);
}

// ================= GEMM core: A-stationary, 32-col B tiles ================
// Block: 256 thr = 4 waves x 16 rows = 64 rows; g = col group (NT x 32
// cols); A-slice (16 rows x 256 k) resident in 8 short8v. B tile 16 KB:
// 4 k-chunks x [32 cols][128 B], XOR (col&7)<<4 (0-conflict, r11-proven).
// ALL stores deferred to epilogue -> loop VMEM = staging loads only ->
// __syncthreads() drains exactly those (safe, compiler-managed).
// MODE 0 (N=512, NT=4): g<2 -> y8 fp8 (cols 0..255); g>=2 -> y2b bf16+bias.
// MODE 1 (N=256, NT=4): g==0 -> zb bf16 (cols 0..127); g==1 -> outf f32+bias.
template<int NT, int MODE>
__device__ __forceinline__ void gemm32_core(
    int g, int ry, int t, const ushort_t* __restrict__ A,
    const ushort_t* __restrict__ Bt, const float* __restrict__ bias,
    unsigned char* __restrict__ out8, ushort_t* __restrict__ outb,
    float* __restrict__ outf, int M, char* Bs)
{
    const int lane = t & 63;
    const int wv   = t >> 6;
    const int row0 = ry * 64 + wv * 16;
    const int cbase = g * NT * 32;
    const int arow = min(row0 + (lane & 15), M - 1);
    const int kq   = (lane >> 4) << 3;

    auto stage = [&](int ct) {
        #pragma unroll
        for (int c = 0; c < 4; ++c) {
            int o    = t * 16;                       // 0..4095 in chunk
            int colI = o >> 7;
            int kb   = (o & 127) ^ ((colI & 7) << 4);
            gload_lds16(Bt + (size_t)(cbase + ct * 32 + colI) * 256
                           + c * 64 + (kb >> 1),
                        Bs + c * 4096 + wv * 1024);
        }
    };

    short8v af[8];
    #pragma unroll
    for (int ks = 0; ks < 8; ++ks)
        af[ks] = *(const short8v*)(A + (size_t)arow * 256 + ks * 32 + kq);

    stage(0);
    __syncthreads();                       // drains A + B(0) loads

    f32x4 acc[NT][2] = {};

    #pragma unroll
    for (int ct = 0; ct < NT; ++ct) {
        __builtin_amdgcn_s_setprio(1);
        #pragma unroll
        for (int ks = 0; ks < 8; ++ks) {
            #pragma unroll
            for (int nj = 0; nj < 2; ++nj) {
                int colI = (nj << 4) + (lane & 15);
                int b = (((ks & 1) << 6) + ((lane >> 4) << 4))
                        ^ ((colI & 7) << 4);
                short8v bg = *(const short8v*)(Bs + (ks >> 1) * 4096
                                               + colI * 128 + b);
                acc[ct][nj] = __builtin_amdgcn_mfma_f32_16x16x32_bf16(
                    af[ks], bg, acc[ct][nj], 0, 0, 0);
            }
        }
        __builtin_amdgcn_s_setprio(0);

        if (ct + 1 < NT) {
            __syncthreads();               // all waves done reading Bs
            stage(ct + 1);                 // 4 loads (only VMEM in flight)
            __syncthreads();               // drain -> Bs(ct+1) valid
        }
    }

    // epilogue: all stores at once (pipeline freely; nothing waits on them)
    #pragma unroll
    for (int ct = 0; ct < NT; ++ct) {
        #pragma unroll
        for (int nj = 0; nj < 2; ++nj) {
            int c = cbase + ct * 32 + (nj << 4) + (lane & 15);
            #pragma unroll
            for (int r = 0; r < 4; ++r) {
                int row = row0 + ((lane >> 4) << 2) + r;
                if (row >= M) continue;
                float v = acc[ct][nj][r];
                if (MODE == 0) {
                    if (g < 2) {
                        unsigned p = __builtin_amdgcn_cvt_pk_fp8_f32(v, v, 0, false);
                        out8[(size_t)row * 256 + c] = (unsigned char)(p & 0xFFu);
                    } else {
                        outb[(size_t)row * 256 + (c - 256)] = f2b(v + bias[c - 256]);
                    }
                } else {
                    if (g == 0) {
                        outb[(size_t)row * 128 + c] = f2b(v);
                    } else {
                        outf[(size_t)row * 128 + (c - 128)] = v + bias[c - 128];
                    }
                }
            }
        }
    }
}

// ================= K1: mhist || cast_f32_bf16 || build_bt =================
__global__ __launch_bounds__(256) void fusedA(
    const int* __restrict__ ei, int* __restrict__ ghist,
    const float* __restrict__ x, ushort_t* __restrict__ xb,
    const float* __restrict__ W1l, const float* __restrict__ W1r,
    const float* __restrict__ W2l, const float* __restrict__ W2r,
    ushort_t* __restrict__ Bt1, ushort_t* __restrict__ Bt2, int E)
{
    __shared__ int hh[256];
    int bid = blockIdx.x, t = threadIdx.x;

    if (bid < RNB) {                         // ---- mhist ----
        hh[t] = 0;
        __syncthreads();
        int base = bid * REPB;
        int lim  = min(base + REPB, E);
        for (int i = base + t; i < lim; i += 256)
            atomicAdd(&hh[ei[E + i] >> 8], 1);
        __syncthreads();
        if (t < RNB) ghist[t * RNB + bid] = hh[t];
    } else if (bid < RNB + 800) {            // ---- cast (800 blocks) ----
        int n4 = N_NODES * 256 / 4;
        int i = (bid - RNB) * 256 + t;
        for (; i < n4; i += 800 * 256) {
            float4 v = ((const float4*)x)[i];
            ushort4 o;
            o.x = f2b(v.x); o.y = f2b(v.y); o.z = f2b(v.z); o.w = f2b(v.w);
            ((ushort4*)xb)[i] = o;
        }
    } else {                                 // ---- build_bt (768 blocks) ----
        int i = (bid - RNB - 800) * 256 + t;
        if (i < 512 * 256) {
            int n = i >> 8, k = i & 255;
            float v = (n < 256) ? W1l[k * 256 + n] : W1r[k * 256 + (n - 256)];
            Bt1[i] = f2b(v);
        }
        int j = i - 512 * 256;
        if (j >= 0 && j < 256 * 256) {
            int n = j >> 8, k = j & 255;
            float v = (n < 128) ? W2l[k * 128 + n] : W2r[k * 128 + (n - 128)];
            Bt2[j] = f2b(v);
        }
    }
}

// ================= scans =================
#define SCAN_B 256
__global__ __launch_bounds__(256) void scan1(
    const int* __restrict__ in, int* __restrict__ excl,
    int* __restrict__ bsum, int N)
{
    __shared__ int s[SCAN_B];
    int t = threadIdx.x;
    int i = blockIdx.x * SCAN_B + t;
    int v = (i < N) ? in[i] : 0;
    s[t] = v;
    __syncthreads();
    for (int off = 1; off < SCAN_B; off <<= 1) {
        int add = (t >= off) ? s[t - off] : 0;
        __syncthreads();
        s[t] += add;
        __syncthreads();
    }
    if (i < N) excl[i] = s[t] - v;
    if (t == SCAN_B - 1) bsum[blockIdx.x] = s[t];
}

__global__ __launch_bounds__(256) void scan2(int* __restrict__ bsum, int nb)
{
    __shared__ int s[SCAN_B];
    int t = threadIdx.x;
    int v = (t < nb) ? bsum[t] : 0;
    s[t] = v;
    __syncthreads();
    for (int off = 1; off < 256; off <<= 1) {
        int add = (t >= off) ? s[t - off] : 0;
        __syncthreads();
        s[t] += add;
        __syncthreads();
    }
    if (t < nb) bsum[t] = s[t] - v;
}

__global__ __launch_bounds__(256) void scan3g(
    int* __restrict__ excl, const int* __restrict__ bsum, int N)
{
    int i = blockIdx.x * SCAN_B + threadIdx.x;
    if (i < N) excl[i] += bsum[blockIdx.x];
}

// ================= K3: mscatter || GEMM1 (MODE 0, NT=4) =================
__global__ __launch_bounds__(256, 4) void fusedB(
    const int* __restrict__ ei, const int* __restrict__ gscan,
    unsigned* __restrict__ packed,
    const ushort_t* __restrict__ A, const ushort_t* __restrict__ Bt,
    const float* __restrict__ bias, unsigned char* __restrict__ out8,
    ushort_t* __restrict__ outb, int E, int M)
{
    __shared__ char BsMem[16384];
    __shared__ int  curMem[256];
    int bid = blockIdx.x, t = threadIdx.x;

    if (bid < RNB) {                         // ---- mscatter ----
        if (t < RNB) curMem[t] = gscan[t * RNB + bid];
        __syncthreads();
        int base = bid * REPB;
        int lim  = min(base + REPB, E);
        for (int i = base + t; i < lim; i += 256) {
            int d = ei[E + i], s = ei[i];
            int pos = atomicAdd(&curMem[d >> 8], 1);
            packed[pos] = ((unsigned)d << 16) | (unsigned)s;
        }
    } else {                                 // ---- GEMM1 (4 col-groups) ----
        int q = bid - RNB;
        gemm32_core<4, 0>(q & 3, q >> 2, t, A, Bt, bias,
                          out8, outb, (float*)nullptr, M, BsMem);
    }
}

// ================= standalone GEMM2 (MODE 1, NT=4) =================
__global__ __launch_bounds__(256, 4) void gemm2k(
    const ushort_t* __restrict__ A, const ushort_t* __restrict__ Bt,
    const float* __restrict__ bias, ushort_t* __restrict__ outb,
    float* __restrict__ outf, int M)
{
    __shared__ char BsMem[16384];
    gemm32_core<4, 1>(blockIdx.x, blockIdx.y, threadIdx.x, A, Bt, bias,
                      (unsigned char*)nullptr, outb, outf, M, BsMem);
}

// ================= bucket_sort =================
__global__ __launch_bounds__(256) void bucket_sort(
    const unsigned* __restrict__ packed, const int* __restrict__ gscan,
    int* __restrict__ col, int* __restrict__ rp, int E)
{
    __shared__ unsigned k1[BCAP];
    __shared__ unsigned k2[BCAP];
    __shared__ int h[256], ss[256], ex[256], cur[256];

    int b = blockIdx.x, t = threadIdx.x;
    int start = gscan[b * RNB];
    int end   = (b + 1 < RNB) ? gscan[(b + 1) * RNB] : E;
    int sz    = min(end - start, BCAP);

    for (int i = t; i < sz; i += 256) k1[i] = packed[start + i];
    h[t] = 0;
    __syncthreads();
    for (int i = t; i < sz; i += 256)
        atomicAdd(&h[(k1[i] >> 16) & 255], 1);
    __syncthreads();
    ss[t] = h[t];
    __syncthreads();
    for (int off = 1; off < 256; off <<= 1) {
        int add = (t >= off) ? ss[t - off] : 0;
        __syncthreads();
        ss[t] += add;
        __syncthreads();
    }
    ex[t] = ss[t] - h[t];
    cur[t] = ex[t];
    __syncthreads();
    for (int i = t; i < sz; i += 256) {
        unsigned key = k1[i];
        int pos = atomicAdd(&cur[(key >> 16) & 255], 1);
        k2[pos] = key;
    }
    __syncthreads();
    for (int i = t; i < sz; i += 256)
        col[start + i] = (int)(k2[i] & 0xFFFFu);
    int dst = (b << 8) + t;
    if (dst <= N_NODES) rp[dst] = start + ex[t];
}

// ================= gathers =================
__global__ __launch_bounds__(256) void fused_gather1(
    const unsigned char* __restrict__ y8, const ushort_t* __restrict__ y2b,
    const int* __restrict__ rp, const int* __restrict__ col,
    ushort_t* __restrict__ h, int N)
{
    int gid  = blockIdx.x * blockDim.x + threadIdx.x;
    int node = gid >> 6;
    int lane = gid & 63;
    if (node >= N) return;
    int rs = rp[node], re = rp[node + 1];

    float acc[4] = {0.f, 0.f, 0.f, 0.f};
    for (int base = rs; base < re; base += 64) {
        int m = re - base; if (m > 64) m = 64;
        int c = (lane < m) ? col[base + lane] : 0;
        int j = 0;
        for (; j + 8 <= m; j += 8) {
            unsigned tv[8];
            #pragma unroll
            for (int q = 0; q < 8; ++q) {
                int sq = __shfl(c, j + q);
                tv[q] = *(const unsigned*)(y8 + (size_t)sq * 256 + lane * 4);
            }
            #pragma unroll
            for (int q = 0; q < 8; ++q) {
                f32x2 lo = __builtin_amdgcn_cvt_pk_f32_fp8(tv[q], false);
                f32x2 hi = __builtin_amdgcn_cvt_pk_f32_fp8(tv[q], true);
                acc[0] += lo[0]; acc[1] += lo[1];
                acc[2] += hi[0]; acc[3] += hi[1];
            }
        }
        for (; j < m; ++j) {
            int sq = __shfl(c, j);
            unsigned tq = *(const unsigned*)(y8 + (size_t)sq * 256 + lane * 4);
            f32x2 lo = __builtin_amdgcn_cvt_pk_f32_fp8(tq, false);
            f32x2 hi = __builtin_amdgcn_cvt_pk_f32_fp8(tq, true);
            acc[0] += lo[0]; acc[1] += lo[1];
            acc[2] += hi[0]; acc[3] += hi[1];
        }
    }

    float s = 1.0f / (float)max(re - rs, 1);
    ushort4 t2 = *(const ushort4*)(y2b + (size_t)node * 256 + lane * 4);
    ushort4 o;
    o.x = f2b(fmaxf(acc[0] * s + b2f(t2.x), 0.f));
    o.y = f2b(fmaxf(acc[1] * s + b2f(t2.y), 0.f));
    o.z = f2b(fmaxf(acc[2] * s + b2f(t2.z), 0.f));
    o.w = f2b(fmaxf(acc[3] * s + b2f(t2.w), 0.f));
    *(ushort4*)(h + (size_t)node * 256 + lane * 4) = o;
}

__global__ __launch_bounds__(256) void fused_gather2(
    const ushort_t* __restrict__ zb, const int* __restrict__ rp,
    const int* __restrict__ col, float* __restrict__ out, int N)
{
    int gid  = blockIdx.x * blockDim.x + threadIdx.x;
    int node = gid >> 6;
    int lane = gid & 63;
    if (node >= N) return;
    int rs = rp[node], re = rp[node + 1];

    float acc[2] = {0.f, 0.f};
    for (int base = rs; base < re; base += 64) {
        int m = re - base; if (m > 64) m = 64;
        int c = (lane < m) ? col[base + lane] : 0;
        int j = 0;
        for (; j + 8 <= m; j += 8) {
            ushort2 tv[8];
            #pragma unroll
            for (int q = 0; q < 8; ++q) {
                int sq = __shfl(c, j + q);
                tv[q] = *(const ushort2*)(zb + (size_t)sq * 128 + lane * 2);
            }
            #pragma unroll
            for (int q = 0; q < 8; ++q) {
                acc[0] += b2f(tv[q].x); acc[1] += b2f(tv[q].y);
            }
        }
        for (; j < m; ++j) {
            int src = __shfl(c, j);
            ushort2 tq = *(const ushort2*)(zb + (size_t)src * 128 + lane * 2);
            acc[0] += b2f(tq.x); acc[1] += b2f(tq.y);
        }
    }

    float s = 1.0f / (float)max(re - rs, 1);
    float2 p = *(float2*)(out + (size_t)node * 128 + lane * 2);
    p.x += acc[0] * s; p.y += acc[1] * s;
    *(float2*)(out + (size_t)node * 128 + lane * 2) = p;
}

extern "C" void kernel_launch(void* const* d_in, const int* in_sizes, int n_in,
                              void* d_out, int out_size, void* d_ws, size_t ws_size,
                              hipStream_t stream)
{
    const float* x   = (const float*)d_in[0];
    const int*   ei  = (const int*)d_in[1];
    const float* W1l = (const float*)d_in[2];
    const float* b1  = (const float*)d_in[3];
    const float* W1r = (const float*)d_in[4];
    const float* W2l = (const float*)d_in[5];
    const float* b2  = (const float*)d_in[6];
    const float* W2r = (const float*)d_in[7];
    float* out = (float*)d_out;

    const int N = N_NODES, E = N_EDGES;
    const int HTOT = RNB * RNB;

    // workspace layout (256 B aligned)
    const size_t off_rp     = 0;
    const size_t off_col    = 204800;
    const size_t off_packed = off_col + 3200000;
    const size_t off_ghist  = off_packed + 3200000;
    const size_t off_gscan  = off_ghist + 160000;
    const size_t off_bsumR  = off_gscan + 160000;
    const size_t off_xb     = off_bsumR + 2048;                // bf16 [N][256]; h overlays
    const size_t off_y8     = off_xb  + (size_t)N * 256 * 2;   // fp8  [N][256]; zb overlays
    const size_t off_y2b    = off_y8  + (size_t)N * 256;       // bf16 [N][256]
    const size_t off_bt1    = off_y2b + (size_t)N * 256 * 2;
    const size_t off_bt2    = off_bt1 + 512 * 256 * 2;
    const size_t required   = off_bt2 + 256 * 256 * 2;         // ~71.3 MB
    if (ws_size < required) return;

    char* ws = (char*)d_ws;
    int*           rp     = (int*)(ws + off_rp);
    int*           col    = (int*)(ws + off_col);
    unsigned*      packed = (unsigned*)(ws + off_packed);
    int*           ghist  = (int*)(ws + off_ghist);
    int*           gscan  = (int*)(ws + off_gscan);
    int*           bsumR  = (int*)(ws + off_bsumR);
    ushort_t*      xb     = (ushort_t*)(ws + off_xb);
    ushort_t*      h      = (ushort_t*)(ws + off_xb);  // overlays xb (dead after GEMM1)
    unsigned char* y8     = (unsigned char*)(ws + off_y8);
    ushort_t*      zb     = (ushort_t*)(ws + off_y8);  // overlays y8 (dead after gather1)
    ushort_t*      y2b    = (ushort_t*)(ws + off_y2b);
    ushort_t*      Bt1    = (ushort_t*)(ws + off_bt1);
    ushort_t*      Bt2    = (ushort_t*)(ws + off_bt2);

    const int snb  = (HTOT + SCAN_B - 1) / SCAN_B;  // 151
    const int mt64 = (N + 63) / 64;                 // 782 row slabs

    // ---- K1: mhist || cast || build_bt ----
    hipLaunchKernelGGL(fusedA, dim3(RNB + 800 + 768), dim3(256), 0, stream,
                       ei, ghist, x, xb, W1l, W1r, W2l, W2r, Bt1, Bt2, E);

    // ---- scans ----
    hipLaunchKernelGGL(scan1, dim3(snb), dim3(SCAN_B), 0, stream, ghist, gscan, bsumR, HTOT);
    hipLaunchKernelGGL(scan2, dim3(1), dim3(SCAN_B), 0, stream, bsumR, snb);
    hipLaunchKernelGGL(scan3g, dim3(snb), dim3(SCAN_B), 0, stream, gscan, bsumR, HTOT);

    // ---- K3: mscatter || GEMM1 ([y8|y2b] = xb@[W1l|W1r] (+b1)) ----
    hipLaunchKernelGGL(fusedB, dim3(RNB + 4 * mt64), dim3(256), 0, stream,
                       ei, gscan, packed, xb, Bt1, b1, y8, y2b, E, N);

    // ---- bucket_sort -> CSR done ----
    hipLaunchKernelGGL(bucket_sort, dim3(RNB), dim3(256), 0, stream,
                       packed, gscan, col, rp, E);

    // ---- gather1: h = relu(mean(y8) + y2b) ----
    hipLaunchKernelGGL(fused_gather1, dim3((N + 3) / 4), dim3(256), 0, stream,
                       y8, y2b, rp, col, h, N);

    // ---- GEMM2: [zb|out] = h@[W2l|W2r] (+b2 on out) ----
    hipLaunchKernelGGL(gemm2k, dim3(2, mt64), dim3(256), 0, stream,
                       h, Bt2, b2, zb, out, N);

    // ---- gather2: out += mean(zb) ----
    hipLaunchKernelGGL(fused_gather2, dim3((N + 3) / 4), dim3(256), 0, stream,
                       zb, rp, col, out, N);
}